// Round 17
// baseline (297.024 us; speedup 1.0000x reference)
//
#include <hip/hip_runtime.h>
#include <hip/hip_bf16.h>
#include <math.h>

// SelfAttentionHybrid via split-bf16 (hi+lo) triple-MFMA fp32 emulation,
// using the algebraic rewrite  QK^T = X (R E^T) X^T:
//   Wt = E @ R^T           (1024^3, K-split x4 + reduce; Wt = (R E^T)^T)
//   Y  = X @ (Wt)^T = X R E^T        (8192x1024x1024, triple)
//   S  = softmax(Y X^T / 32)         (4 x 2048x2048, K=1024, triple, 256^2 tile,
//                                     16 waves, 32x32x16 MFMA + col-major LDS)
//   O  = sigmoid(S @ X)              (4 x 2048x1024, K=2048, single bf16 MFMA,
//                                     BK=64: two K-halves/buffer)
// Triple GEMMs: acc += Ahi*Bhi + Ahi*Blo + Alo*Bhi  (lo*lo ~2^-18 dropped).
// S-gemm change this round: 32x32x16 (8.07cyc vs 2x4.85 = -17% MFMA-pipe) with
// column-major-per-kgroup LDS (off = g*2048 + row*8) -> fragment reads are
// 512B-contiguous per half-wave = conflict-free by construction (R7's 4-way
// conflict was inherent to 64B row-major rows). Staging keeps linear t*8 LDS
// dest; per-lane GLOBAL address remapped to (row=t&255, g=t>>8).

using u16 = unsigned short;
using short8 = __attribute__((ext_vector_type(8))) short;
using f32x4  = __attribute__((ext_vector_type(4))) float;
using f32x16 = __attribute__((ext_vector_type(16))) float;

#define MFB(a, b, c)   __builtin_amdgcn_mfma_f32_16x16x32_bf16((a), (b), (c), 0, 0, 0)
#define MFB32(a, b, c) __builtin_amdgcn_mfma_f32_32x32x16_bf16((a), (b), (c), 0, 0, 0)

__device__ static inline u16 f2bf(float f) {
    union { __hip_bfloat16 h; u16 u; } cv; cv.h = __float2bfloat16(f); return cv.u;
}
__device__ static inline float bf2f(u16 u) {
    union { __hip_bfloat16 h; u16 u; } cv; cv.u = u; return __bfloat162float(cv.h);
}
__device__ static inline void split2(float v, u16& h, u16& l) {
    h = f2bf(v);
    l = f2bf(v - bf2f(h));
}

__device__ static inline void gload16(const u16* g, u16* l) {
    __builtin_amdgcn_global_load_lds(
        (const __attribute__((address_space(1))) void*)g,
        (__attribute__((address_space(3))) void*)l, 16, 0, 0);
}

// Row-major LDS tile (128^2 kernels): [rows][32 bf16], 16B chunk XOR-swizzled.
__device__ static inline short8 ldfrag(const u16* sm, int row, int g) {
    const int off = row * 32 + ((g ^ ((row >> 1) & 3)) << 3);
    return *reinterpret_cast<const short8*>(sm + off);
}

// Column-major-per-kgroup LDS tile (S-gemm): off = g*2048 + row*8 (u16).
__device__ static inline short8 ldcol(const u16* sm, int row, int g) {
    return *reinterpret_cast<const short8*>(sm + g * 2048 + row * 8);
}

enum { EP_F32 = 0, EP_HILO = 1, EP_SIG = 2 };

// ---------------------------------------------------------------------------
// 128^2 tile kernel (W, Y, PV). 256 thr / 4 waves (2x2), wave tile 64x64.
// KH = K-halves per LDS buffer: KH=1 -> BK=32 (triple), KH=2 -> BK=64 (PV).
// ---------------------------------------------------------------------------
template<int EPI, bool TRIPLE, int KH>
__global__ __launch_bounds__(256)
void gemm_split(const u16* __restrict__ Ahi, const u16* __restrict__ Alo,
                const u16* __restrict__ Bhi, const u16* __restrict__ Blo,
                float* __restrict__ Cf, u16* __restrict__ Chi, u16* __restrict__ Clo,
                int K, int lda, int ldb, int ldc,
                long sA, long sB, long sC, float alpha)
{
    const int z = blockIdx.z;
    Ahi += z * sA;
    Bhi += z * sB;
    if (TRIPLE) { Alo += z * sA; Blo += z * sB; }
    if (EPI == EP_HILO) { Chi += z * sC; Clo += z * sC; }
    else                { Cf  += z * sC; }

    constexpr int AUNIT = TRIPLE ? 8192 : 4096;   // u16 per K-half, A side
    constexpr int BUFSZ = KH * 2 * AUNIT;         // A halves then B halves
    __shared__ __align__(16) u16 smem[2 * BUFSZ];

    const int t = threadIdx.x;
    const int wave = t >> 6, lane = t & 63;
    const int row0 = blockIdx.y * 128, col0 = blockIdx.x * 128;

    const int rr = t >> 2, cc = t & 3;
    const int gg = cc ^ ((rr >> 1) & 3);
    const u16* gAh = Ahi + (long)(row0 + rr) * lda + gg * 8;
    const u16* gBh = Bhi + (long)(col0 + rr) * ldb + gg * 8;
    const u16* gAl = TRIPLE ? (Alo + (long)(row0 + rr) * lda + gg * 8) : nullptr;
    const u16* gBl = TRIPLE ? (Blo + (long)(col0 + rr) * ldb + gg * 8) : nullptr;
    const long a2 = (long)64 * lda, b2 = (long)64 * ldb;

    auto STAGE = [&](int buf, int k0) {
        u16* base = smem + buf * BUFSZ + t * 8;
        #pragma unroll
        for (int kh = 0; kh < KH; kh++) {
            const int kk = k0 + kh * 32;
            u16* dA = base + kh * AUNIT;
            u16* dB = base + KH * AUNIT + kh * AUNIT;
            gload16(gAh + kk,      dA);
            gload16(gAh + kk + a2, dA + 2048);
            gload16(gBh + kk,      dB);
            gload16(gBh + kk + b2, dB + 2048);
            if (TRIPLE) {
                gload16(gAl + kk,      dA + 4096);
                gload16(gAl + kk + a2, dA + 6144);
                gload16(gBl + kk,      dB + 4096);
                gload16(gBl + kk + b2, dB + 6144);
            }
        }
    };

    f32x4 acc[4][4];
    #pragma unroll
    for (int m = 0; m < 4; m++)
        #pragma unroll
        for (int n = 0; n < 4; n++)
            acc[m][n] = (f32x4){0.f, 0.f, 0.f, 0.f};

    const int lr = lane & 15, lg = lane >> 4;
    const int wm = (wave >> 1) * 64, wn = (wave & 1) * 64;
    const int NT = K / (32 * KH);

    STAGE(0, 0);

    for (int tk = 0; tk < NT; ++tk) {
        __syncthreads();    // implicit vmcnt(0)+lgkmcnt(0): staging landed, reads drained
        const u16* sb = smem + (tk & 1) * BUFSZ;
        if (tk + 1 < NT) STAGE((tk + 1) & 1, (tk + 1) * 32 * KH);

        #pragma unroll
        for (int kh = 0; kh < KH; kh++) {
            const u16* sAh = sb + kh * AUNIT;
            const u16* sAl = sAh + 4096;
            const u16* sBh = sb + KH * AUNIT + kh * AUNIT;
            const u16* sBl = sBh + 4096;

            short8 bh[4], bl[4], ah[4], al[4];
            #pragma unroll
            for (int n = 0; n < 4; n++) {
                bh[n] = ldfrag(sBh, wn + n * 16 + lr, lg);
                if (TRIPLE) bl[n] = ldfrag(sBl, wn + n * 16 + lr, lg);
            }
            #pragma unroll
            for (int m = 0; m < 4; m++) {
                ah[m] = ldfrag(sAh, wm + m * 16 + lr, lg);
                if (TRIPLE) al[m] = ldfrag(sAl, wm + m * 16 + lr, lg);
            }
            __builtin_amdgcn_s_setprio(1);
            #pragma unroll
            for (int m = 0; m < 4; m++) {
                #pragma unroll
                for (int n = 0; n < 4; n++) {
                    acc[m][n] = MFB(ah[m], bh[n], acc[m][n]);
                    if (TRIPLE) {
                        acc[m][n] = MFB(ah[m], bl[n], acc[m][n]);
                        acc[m][n] = MFB(al[m], bh[n], acc[m][n]);
                    }
                }
            }
            __builtin_amdgcn_s_setprio(0);
        }
    }

    // ---- epilogue: C/D layout col=lane&15, row=(lane>>4)*4+reg ----
    #pragma unroll
    for (int m = 0; m < 4; m++) {
        #pragma unroll
        for (int n = 0; n < 4; n++) {
            #pragma unroll
            for (int r = 0; r < 4; r++) {
                const int grow = row0 + wm + m * 16 + lg * 4 + r;
                const int gcol = col0 + wn + n * 16 + lr;
                const float v = alpha * acc[m][n][r];
                const long o = (long)grow * ldc + gcol;
                if (EPI == EP_F32) {
                    Cf[o] = v;
                } else if (EPI == EP_SIG) {
                    Cf[o] = 1.0f / (1.0f + __expf(-v));
                } else {
                    u16 h, l; split2(v, h, l);
                    Chi[o] = h; Clo[o] = l;
                }
            }
        }
    }
}

// ---------------------------------------------------------------------------
// 256^2 triple kernel (S-gemm). 1024 thr / 16 waves (4M x 4N), wave tile
// 64x64 = 2x2 frags of 32x32 (32x32x16 MFMA). LDS 128 KiB:
// [2 buf][Ah|Al|Bh|Bl x 16KB], each operand COLUMN-MAJOR per k-group:
// off = g*2048 + row*8 (u16). Staging: thread t's linear LDS slot t*8
// corresponds to (row = t&255, g = t>>8) -> per-lane global address remapped
// accordingly (gload_lds allows per-lane source). Fragment read: lanes 0-31
// at 16B stride (contiguous 512B) -> conflict-free. One __syncthreads/K-tile.
// Grid is (8,8,B); flat%8 == XCD -> 2x4 super-tile remap for L2 locality.
// ---------------------------------------------------------------------------
__global__ __launch_bounds__(1024)
void gemm_triple_256(const u16* __restrict__ Ahi, const u16* __restrict__ Alo,
                     const u16* __restrict__ Bhi, const u16* __restrict__ Blo,
                     float* __restrict__ Cf,
                     int K, int lda, int ldb, int ldc,
                     long sA, long sB, long sC, float alpha)
{
    const int z = blockIdx.z;
    Ahi += z * sA; Alo += z * sA;
    Bhi += z * sB; Blo += z * sB;
    Cf  += z * sC;

    __shared__ __align__(16) u16 smem[65536];   // 128 KiB

    const int t = threadIdx.x;
    const int wave = t >> 6, lane = t & 63;
    const int l31 = lane & 31, l5 = lane >> 5;

    const int u = blockIdx.x + 8 * blockIdx.y;
    const int reg = u & 7, j = u >> 3;
    const int bx = 2 * (reg & 3) + (j & 1);
    const int by = 4 * (reg >> 2) + (j >> 1);
    const int row0 = by * 256, col0 = bx * 256;
    const int wm = (wave >> 2) * 64, wn = (wave & 3) * 64;

    // staging: thread t -> LDS (row = t&255, g = t>>8); fetch matching global
    const int sr = t & 255, sgc = t >> 8;
    const u16* gAh = Ahi + (long)(row0 + sr) * lda + sgc * 8;
    const u16* gAl = Alo + (long)(row0 + sr) * lda + sgc * 8;
    const u16* gBh = Bhi + (long)(col0 + sr) * ldb + sgc * 8;
    const u16* gBl = Blo + (long)(col0 + sr) * ldb + sgc * 8;

    f32x16 acc[2][2];
    #pragma unroll
    for (int m = 0; m < 2; m++)
        #pragma unroll
        for (int n = 0; n < 2; n++)
            #pragma unroll
            for (int r = 0; r < 16; r++)
                acc[m][n][r] = 0.f;

    const int NT = K >> 5;

    {
        u16* d = smem + t * 8;
        gload16(gAh, d);
        gload16(gAl, d + 8192);
        gload16(gBh, d + 16384);
        gload16(gBl, d + 24576);
    }

    for (int tk = 0; tk < NT; ++tk) {
        __syncthreads();    // implicit vmcnt(0)+lgkmcnt(0)
        const u16* sb = smem + (tk & 1) * 32768;
        if (tk + 1 < NT) {
            const int kn = (tk + 1) << 5;
            u16* d = smem + ((tk + 1) & 1) * 32768 + t * 8;
            gload16(gAh + kn, d);
            gload16(gAl + kn, d + 8192);
            gload16(gBh + kn, d + 16384);
            gload16(gBl + kn, d + 24576);
        }
        const u16* sAh = sb;
        const u16* sAl = sb + 8192;
        const u16* sBh = sb + 16384;
        const u16* sBl = sb + 24576;

        #pragma unroll
        for (int kk = 0; kk < 2; kk++) {
            const int g = 2 * kk + l5;
            short8 bh[2], bl[2], ah[2], al[2];
            #pragma unroll
            for (int n = 0; n < 2; n++) {
                bh[n] = ldcol(sBh, wn + n * 32 + l31, g);
                bl[n] = ldcol(sBl, wn + n * 32 + l31, g);
            }
            #pragma unroll
            for (int m = 0; m < 2; m++) {
                ah[m] = ldcol(sAh, wm + m * 32 + l31, g);
                al[m] = ldcol(sAl, wm + m * 32 + l31, g);
            }
            __builtin_amdgcn_s_setprio(1);
            #pragma unroll
            for (int m = 0; m < 2; m++)
                #pragma unroll
                for (int n = 0; n < 2; n++) {
                    acc[m][n] = MFB32(ah[m], bh[n], acc[m][n]);
                    acc[m][n] = MFB32(ah[m], bl[n], acc[m][n]);
                    acc[m][n] = MFB32(al[m], bh[n], acc[m][n]);
                }
            __builtin_amdgcn_s_setprio(0);
        }
    }

    // ---- epilogue: 32x32 C/D layout col=lane&31, row=(r&3)+8*(r>>2)+4*(lane>>5)
    #pragma unroll
    for (int m = 0; m < 2; m++) {
        #pragma unroll
        for (int n = 0; n < 2; n++) {
            #pragma unroll
            for (int r = 0; r < 16; r++) {
                const int grow = row0 + wm + m * 32 + (r & 3) + 8 * (r >> 2) + 4 * l5;
                const int gcol = col0 + wn + n * 32 + l31;
                Cf[(long)grow * ldc + gcol] = alpha * acc[m][n][r];
            }
        }
    }
}

// merged float -> (hi,lo) bf16 split for X, R, E in one launch
__global__ __launch_bounds__(256)
void split_rm3(const float* __restrict__ in0, u16* __restrict__ hi0, u16* __restrict__ lo0, long n0,
               const float* __restrict__ in1, u16* __restrict__ hi1, u16* __restrict__ lo1, long n1,
               const float* __restrict__ in2, u16* __restrict__ hi2, u16* __restrict__ lo2)
{
    long i = ((long)blockIdx.x * 256 + threadIdx.x) * 4;
    const float* in; u16 *hi, *lo;
    if (i < n0)           { in = in0; hi = hi0; lo = lo0; }
    else if (i < n0 + n1) { i -= n0; in = in1; hi = hi1; lo = lo1; }
    else                  { i -= n0 + n1; in = in2; hi = hi2; lo = lo2; }
    const float4 v = *reinterpret_cast<const float4*>(in + i);
    ushort4 h, l;
    split2(v.x, h.x, l.x);
    split2(v.y, h.y, l.y);
    split2(v.z, h.z, l.z);
    split2(v.w, h.w, l.w);
    *reinterpret_cast<ushort4*>(hi + i) = h;
    *reinterpret_cast<ushort4*>(lo + i) = l;
}

// sum 4 partial fp32 buffers (stride n) -> (hi,lo) bf16
__global__ __launch_bounds__(256)
void reduce4_split(const float* __restrict__ p, u16* __restrict__ hi, u16* __restrict__ lo,
                   long n)
{
    const long i = ((long)blockIdx.x * 256 + threadIdx.x) * 4;
    const float4 a = *reinterpret_cast<const float4*>(p + i);
    const float4 b = *reinterpret_cast<const float4*>(p + n + i);
    const float4 c = *reinterpret_cast<const float4*>(p + 2 * n + i);
    const float4 d = *reinterpret_cast<const float4*>(p + 3 * n + i);
    ushort4 h, l;
    split2((a.x + b.x) + (c.x + d.x), h.x, l.x);
    split2((a.y + b.y) + (c.y + d.y), h.y, l.y);
    split2((a.z + b.z) + (c.z + d.z), h.z, l.z);
    split2((a.w + b.w) + (c.w + d.w), h.w, l.w);
    *reinterpret_cast<ushort4*>(hi + i) = h;
    *reinterpret_cast<ushort4*>(lo + i) = l;
}

// float (R x C) -> transposed (C x R) bf16 hi (+lo if HILO); batched via blockIdx.z
template<bool HILO>
__global__ __launch_bounds__(256)
void split_tr(const float* __restrict__ in, u16* __restrict__ hi, u16* __restrict__ lo,
              int R, int C, long sIn, long sOut)
{
    in += (long)blockIdx.z * sIn;
    hi += (long)blockIdx.z * sOut;
    if (HILO) lo += (long)blockIdx.z * sOut;

    __shared__ float tile[32][33];
    const int tx = threadIdx.x & 31, ty = threadIdx.x >> 5;   // 32 x 8
    const int r0 = blockIdx.y * 32, c0 = blockIdx.x * 32;

    #pragma unroll
    for (int j = 0; j < 4; j++)
        tile[ty * 4 + j][tx] = in[(long)(r0 + ty * 4 + j) * C + c0 + tx];
    __syncthreads();

    #pragma unroll
    for (int j = 0; j < 4; j++) {
        const int oc = ty * 4 + j;
        const float v = tile[tx][oc];
        u16 h, l; split2(v, h, l);
        const long o = (long)(c0 + oc) * R + r0 + tx;
        hi[o] = h;
        if (HILO) lo[o] = l;
    }
}

// row softmax over 2048 fp32 logits -> bf16 (hi only) probabilities
__global__ __launch_bounds__(256)
void softmax_hi(const float* __restrict__ S, u16* __restrict__ hi)
{
    const int NC = 2048;
    const long base = (long)blockIdx.x * NC;
    const float* p = S + base;
    const int tid = threadIdx.x;

    float4 v0 = reinterpret_cast<const float4*>(p)[tid];
    float4 v1 = reinterpret_cast<const float4*>(p)[tid + 256];

    float m = fmaxf(fmaxf(fmaxf(v0.x, v0.y), fmaxf(v0.z, v0.w)),
                    fmaxf(fmaxf(v1.x, v1.y), fmaxf(v1.z, v1.w)));
    #pragma unroll
    for (int off = 1; off < 64; off <<= 1)
        m = fmaxf(m, __shfl_xor(m, off));

    __shared__ float redm[4];
    __shared__ float reds[4];
    const int wave = tid >> 6, lane = tid & 63;
    if (lane == 0) redm[wave] = m;
    __syncthreads();
    m = fmaxf(fmaxf(redm[0], redm[1]), fmaxf(redm[2], redm[3]));

    v0.x = __expf(v0.x - m); v0.y = __expf(v0.y - m);
    v0.z = __expf(v0.z - m); v0.w = __expf(v0.w - m);
    v1.x = __expf(v1.x - m); v1.y = __expf(v1.y - m);
    v1.z = __expf(v1.z - m); v1.w = __expf(v1.w - m);

    float s = (v0.x + v0.y + v0.z + v0.w) + (v1.x + v1.y + v1.z + v1.w);
    #pragma unroll
    for (int off = 1; off < 64; off <<= 1)
        s += __shfl_xor(s, off);
    if (lane == 0) reds[wave] = s;
    __syncthreads();
    s = (reds[0] + reds[1]) + (reds[2] + reds[3]);

    const float inv = 1.0f / s;
    ushort4 h0, h1;
    h0.x = f2bf(v0.x * inv); h0.y = f2bf(v0.y * inv);
    h0.z = f2bf(v0.z * inv); h0.w = f2bf(v0.w * inv);
    h1.x = f2bf(v1.x * inv); h1.y = f2bf(v1.y * inv);
    h1.z = f2bf(v1.z * inv); h1.w = f2bf(v1.w * inv);

    reinterpret_cast<ushort4*>(hi + base)[tid]       = h0;
    reinterpret_cast<ushort4*>(hi + base)[tid + 256] = h1;
}

extern "C" void kernel_launch(void* const* d_in, const int* in_sizes, int n_in,
                              void* d_out, int out_size, void* d_ws, size_t ws_size,
                              hipStream_t stream)
{
    (void)in_sizes; (void)n_in; (void)out_size; (void)ws_size;
    const float* X = (const float*)d_in[0];   // (4,2048,1024)
    const float* R = (const float*)d_in[1];   // (1024,1024)
    const float* E = (const float*)d_in[2];   // (1024,1024)
    float* out = (float*)d_out;

    const int B = 4, SQ = 2048, D = 1024;
    const long NDX = (long)B * SQ * D;        // 8388608
    const long DD  = (long)D * D;             // 1048576
    const long SS  = (long)B * SQ * SQ;       // 16777216
    const long M16 = 8388608;                 // u16 elems per 16 MiB

    u16* wsu = (u16*)d_ws;
    // [0,32MB):  Xhi(16) Xlo(16)      -> after S-gemm: Xthi at [0,16)
    // [32,64MB): Rhi Rlo Ehi Elo (8)  -> Yhi(16) Ylo(16) -> Shi(32)
    // [64,128MB): Wpart(16) Wthi/Wtlo(4, at 80MB) -> Sf(64)
    u16* Xhi  = wsu;
    u16* Xlo  = Xhi + NDX;
    u16* Rhi  = wsu + 2 * M16;                // 32MB
    u16* Rlo  = Rhi + DD;
    u16* Ehi  = Rlo + DD;
    u16* Elo  = Ehi + DD;
    u16* Yhi  = wsu + 2 * M16;                // 32MB (R/E dead by then)
    u16* Ylo  = Yhi + NDX;
    u16* Shi  = wsu + 2 * M16;                // 32MB (Y dead by then)
    u16* Xthi = wsu;                          // (X splits dead by then)
    float* Wpart = (float*)(wsu + 4 * M16);   // 64MB: 4 x DD fp32 = 16MB
    u16* Wthi = wsu + 5 * M16;                // 80MB
    u16* Wtlo = Wthi + DD;
    float* Sf = (float*)(wsu + 4 * M16);      // 64MB..128MB (Wpart/Wt dead)

    dim3 thr(256);

    // split all three inputs in ONE launch (X 8192 blocks + R 1024 + E 1024)
    split_rm3<<<dim3((unsigned)((NDX + 2 * DD) / 1024)), thr, 0, stream>>>(
        X, Xhi, Xlo, NDX, R, Rhi, Rlo, DD, E, Ehi, Elo);

    // Wt = E @ R^T  (= (R E^T)^T), K-split x4 into fp32 partials + reduce
    gemm_split<EP_F32, true, 1><<<dim3(D / 128, D / 128, 4), thr, 0, stream>>>(
        Ehi, Elo, Rhi, Rlo, Wpart, nullptr, nullptr,
        256, D, D, D, 256, 256, DD, 1.0f);
    reduce4_split<<<dim3((unsigned)(DD / 1024)), thr, 0, stream>>>(Wpart, Wthi, Wtlo, DD);

    // Y = X @ Wt^T = X R E^T  -> hi/lo (8192 x 1024)
    gemm_split<EP_HILO, true, 1><<<dim3(D / 128, (B * SQ) / 128, 1), thr, 0, stream>>>(
        Xhi, Xlo, Wthi, Wtlo, nullptr, Yhi, Ylo,
        D, D, D, D, 0, 0, 0, 1.0f);

    // S = Y X^T / 32 — 16-wave 256^2, 32x32x16 MFMA + col-major LDS
    gemm_triple_256<<<dim3(SQ / 256, SQ / 256, B), dim3(1024), 0, stream>>>(
        Yhi, Ylo, Xhi, Xlo, Sf,
        D, D, D, SQ,
        (long)SQ * D, (long)SQ * D, (long)SQ * SQ, 0.03125f);

    // softmax fp32 -> probability hi into Shi (Y dead)
    softmax_hi<<<dim3(B * SQ), thr, 0, stream>>>(Sf, Shi);

    // Xt (per batch 1024x2048) hi-only (X splits dead)
    split_tr<false><<<dim3(D / 32, SQ / 32, B), thr, 0, stream>>>(
        X, Xthi, nullptr, SQ, D, (long)SQ * D, (long)SQ * D);

    // O = sigmoid(S @ X), single-bf16 MFMA, BK=64 (KH=2)
    gemm_split<EP_SIG, false, 2><<<dim3(D / 128, SQ / 128, B), thr, 0, stream>>>(
        Shi, nullptr, Xthi, nullptr, out, nullptr, nullptr,
        SQ, SQ, SQ, D,
        (long)SQ * SQ, (long)SQ * D, (long)SQ * D, 1.0f);
}

// Round 18
// 240.064 us; speedup vs baseline: 1.2373x; 1.2373x over previous
//
#include <hip/hip_runtime.h>
#include <hip/hip_bf16.h>
#include <math.h>

// SelfAttentionHybrid via split-bf16 (hi+lo) triple-MFMA fp32 emulation,
// using the algebraic rewrite  QK^T = X (R E^T) X^T:
//   Wt = E @ R^T           (1024^3, K-split x4 + reduce; Wt = (R E^T)^T)
//   Y  = X @ (Wt)^T = X R E^T        (8192x1024x1024, triple)
//   S  = softmax(Y X^T / 32)         (4 x 2048x2048, K=1024, triple, 256^2 tile,
//                                     1024 thr / 16 waves = 4 waves/SIMD)
//   O  = sigmoid(S @ X)              (4 x 2048x1024, K=2048, single bf16 MFMA,
//                                     BK=64: two K-halves/buffer)
// Triple GEMMs: acc += Ahi*Bhi + Ahi*Blo + Alo*Bhi  (lo*lo ~2^-18 dropped).
// Session-optimum configuration (R14/R16, 240.7-240.8 us, verified twice).
// 32x32x16 MFMA is structurally incompatible with gload_lds staging here:
// row-major 64B rows -> inherent 4-way LDS read conflict (R7); col-major
// layout fixes reads but un-coalesces the forced-linear LDS staging (R17).

using u16 = unsigned short;
using short8 = __attribute__((ext_vector_type(8))) short;
using f32x4  = __attribute__((ext_vector_type(4))) float;

#define MFB(a, b, c) __builtin_amdgcn_mfma_f32_16x16x32_bf16((a), (b), (c), 0, 0, 0)

__device__ static inline u16 f2bf(float f) {
    union { __hip_bfloat16 h; u16 u; } cv; cv.h = __float2bfloat16(f); return cv.u;
}
__device__ static inline float bf2f(u16 u) {
    union { __hip_bfloat16 h; u16 u; } cv; cv.u = u; return __bfloat162float(cv.h);
}
__device__ static inline void split2(float v, u16& h, u16& l) {
    h = f2bf(v);
    l = f2bf(v - bf2f(h));
}

__device__ static inline void gload16(const u16* g, u16* l) {
    __builtin_amdgcn_global_load_lds(
        (const __attribute__((address_space(1))) void*)g,
        (__attribute__((address_space(3))) void*)l, 16, 0, 0);
}

// LDS tile layout: [rows][32 bf16], row = 64B. 16B chunk index is
// XOR-swizzled: chunk slot c holds k-group g = c ^ ((row>>1)&3).
// Readers (16 consecutive rows at fixed k-group) spread 2-way max (free).
__device__ static inline short8 ldfrag(const u16* sm, int row, int g) {
    const int off = row * 32 + ((g ^ ((row >> 1) & 3)) << 3);
    return *reinterpret_cast<const short8*>(sm + off);
}

enum { EP_F32 = 0, EP_HILO = 1, EP_SIG = 2 };

// ---------------------------------------------------------------------------
// 128^2 tile kernel (W, Y, PV). 256 thr / 4 waves (2x2), wave tile 64x64.
// KH = K-halves (of 32) per LDS buffer: KH=1 -> BK=32 (triple paths, proven),
// KH=2 -> BK=64 (PV: half the barriers, dbuf 2x32KB, still 2 blocks/CU).
// Double-buffered; all frag reads hoisted per K-half.
// ---------------------------------------------------------------------------
template<int EPI, bool TRIPLE, int KH>
__global__ __launch_bounds__(256)
void gemm_split(const u16* __restrict__ Ahi, const u16* __restrict__ Alo,
                const u16* __restrict__ Bhi, const u16* __restrict__ Blo,
                float* __restrict__ Cf, u16* __restrict__ Chi, u16* __restrict__ Clo,
                int K, int lda, int ldb, int ldc,
                long sA, long sB, long sC, float alpha)
{
    const int z = blockIdx.z;
    Ahi += z * sA;
    Bhi += z * sB;
    if (TRIPLE) { Alo += z * sA; Blo += z * sB; }
    if (EPI == EP_HILO) { Chi += z * sC; Clo += z * sC; }
    else                { Cf  += z * sC; }

    constexpr int AUNIT = TRIPLE ? 8192 : 4096;   // u16 per K-half, A side
    constexpr int BUFSZ = KH * 2 * AUNIT;         // A halves then B halves
    __shared__ __align__(16) u16 smem[2 * BUFSZ];

    const int t = threadIdx.x;
    const int wave = t >> 6, lane = t & 63;
    const int row0 = blockIdx.y * 128, col0 = blockIdx.x * 128;

    const int rr = t >> 2, cc = t & 3;
    const int gg = cc ^ ((rr >> 1) & 3);
    const u16* gAh = Ahi + (long)(row0 + rr) * lda + gg * 8;
    const u16* gBh = Bhi + (long)(col0 + rr) * ldb + gg * 8;
    const u16* gAl = TRIPLE ? (Alo + (long)(row0 + rr) * lda + gg * 8) : nullptr;
    const u16* gBl = TRIPLE ? (Blo + (long)(col0 + rr) * ldb + gg * 8) : nullptr;
    const long a2 = (long)64 * lda, b2 = (long)64 * ldb;

    auto STAGE = [&](int buf, int k0) {
        u16* base = smem + buf * BUFSZ + t * 8;
        #pragma unroll
        for (int kh = 0; kh < KH; kh++) {
            const int kk = k0 + kh * 32;
            u16* dA = base + kh * AUNIT;
            u16* dB = base + KH * AUNIT + kh * AUNIT;
            gload16(gAh + kk,      dA);
            gload16(gAh + kk + a2, dA + 2048);
            gload16(gBh + kk,      dB);
            gload16(gBh + kk + b2, dB + 2048);
            if (TRIPLE) {
                gload16(gAl + kk,      dA + 4096);
                gload16(gAl + kk + a2, dA + 6144);
                gload16(gBl + kk,      dB + 4096);
                gload16(gBl + kk + b2, dB + 6144);
            }
        }
    };

    f32x4 acc[4][4];
    #pragma unroll
    for (int m = 0; m < 4; m++)
        #pragma unroll
        for (int n = 0; n < 4; n++)
            acc[m][n] = (f32x4){0.f, 0.f, 0.f, 0.f};

    const int lr = lane & 15, lg = lane >> 4;
    const int wm = (wave >> 1) * 64, wn = (wave & 1) * 64;
    const int NT = K / (32 * KH);

    STAGE(0, 0);

    for (int tk = 0; tk < NT; ++tk) {
        __syncthreads();    // implicit vmcnt(0)+lgkmcnt(0): staging landed, reads drained
        const u16* sb = smem + (tk & 1) * BUFSZ;
        if (tk + 1 < NT) STAGE((tk + 1) & 1, (tk + 1) * 32 * KH);

        #pragma unroll
        for (int kh = 0; kh < KH; kh++) {
            const u16* sAh = sb + kh * AUNIT;
            const u16* sAl = sAh + 4096;
            const u16* sBh = sb + KH * AUNIT + kh * AUNIT;
            const u16* sBl = sBh + 4096;

            short8 bh[4], bl[4], ah[4], al[4];
            #pragma unroll
            for (int n = 0; n < 4; n++) {
                bh[n] = ldfrag(sBh, wn + n * 16 + lr, lg);
                if (TRIPLE) bl[n] = ldfrag(sBl, wn + n * 16 + lr, lg);
            }
            #pragma unroll
            for (int m = 0; m < 4; m++) {
                ah[m] = ldfrag(sAh, wm + m * 16 + lr, lg);
                if (TRIPLE) al[m] = ldfrag(sAl, wm + m * 16 + lr, lg);
            }
            __builtin_amdgcn_s_setprio(1);
            #pragma unroll
            for (int m = 0; m < 4; m++) {
                #pragma unroll
                for (int n = 0; n < 4; n++) {
                    acc[m][n] = MFB(ah[m], bh[n], acc[m][n]);
                    if (TRIPLE) {
                        acc[m][n] = MFB(ah[m], bl[n], acc[m][n]);
                        acc[m][n] = MFB(al[m], bh[n], acc[m][n]);
                    }
                }
            }
            __builtin_amdgcn_s_setprio(0);
        }
    }

    // ---- epilogue: C/D layout col=lane&15, row=(lane>>4)*4+reg ----
    #pragma unroll
    for (int m = 0; m < 4; m++) {
        #pragma unroll
        for (int n = 0; n < 4; n++) {
            #pragma unroll
            for (int r = 0; r < 4; r++) {
                const int grow = row0 + wm + m * 16 + lg * 4 + r;
                const int gcol = col0 + wn + n * 16 + lr;
                const float v = alpha * acc[m][n][r];
                const long o = (long)grow * ldc + gcol;
                if (EPI == EP_F32) {
                    Cf[o] = v;
                } else if (EPI == EP_SIG) {
                    Cf[o] = 1.0f / (1.0f + __expf(-v));
                } else {
                    u16 h, l; split2(v, h, l);
                    Chi[o] = h; Clo[o] = l;
                }
            }
        }
    }
}

// ---------------------------------------------------------------------------
// 256^2 triple kernel (S-gemm). 1024 thr / 16 waves (4M x 4N), wave tile
// 64x64. LDS 128 KiB: [2 buf][Ah(16KB)|Al|Bh|Bl]. One __syncthreads per
// K-tile; B-frags hoisted; 4 waves/SIMD (R12-verified +MfmaUtil).
// Grid is (8,8,B); flat%8 == XCD -> 2x4 super-tile remap for L2 locality.
// ---------------------------------------------------------------------------
__global__ __launch_bounds__(1024)
void gemm_triple_256(const u16* __restrict__ Ahi, const u16* __restrict__ Alo,
                     const u16* __restrict__ Bhi, const u16* __restrict__ Blo,
                     float* __restrict__ Cf,
                     int K, int lda, int ldb, int ldc,
                     long sA, long sB, long sC, float alpha)
{
    const int z = blockIdx.z;
    Ahi += z * sA; Alo += z * sA;
    Bhi += z * sB; Blo += z * sB;
    Cf  += z * sC;

    __shared__ __align__(16) u16 smem[65536];   // 128 KiB

    const int t = threadIdx.x;
    const int wave = t >> 6, lane = t & 63;
    const int lr = lane & 15, lg = lane >> 4;

    const int u = blockIdx.x + 8 * blockIdx.y;
    const int reg = u & 7, j = u >> 3;
    const int bx = 2 * (reg & 3) + (j & 1);
    const int by = 4 * (reg >> 2) + (j >> 1);
    const int row0 = by * 256, col0 = bx * 256;
    const int wm = (wave >> 2) * 64, wn = (wave & 3) * 64;

    const int srow = t >> 2;
    const int sg = (t & 3) ^ ((srow >> 1) & 3);
    const u16* gAh = Ahi + (long)(row0 + srow) * lda + sg * 8;
    const u16* gAl = Alo + (long)(row0 + srow) * lda + sg * 8;
    const u16* gBh = Bhi + (long)(col0 + srow) * ldb + sg * 8;
    const u16* gBl = Blo + (long)(col0 + srow) * ldb + sg * 8;

    f32x4 acc[4][4];
    #pragma unroll
    for (int m = 0; m < 4; m++)
        #pragma unroll
        for (int n = 0; n < 4; n++)
            acc[m][n] = (f32x4){0.f, 0.f, 0.f, 0.f};

    const int NT = K >> 5;

    {
        u16* d = smem + t * 8;
        gload16(gAh, d);
        gload16(gAl, d + 8192);
        gload16(gBh, d + 16384);
        gload16(gBl, d + 24576);
    }

    for (int tk = 0; tk < NT; ++tk) {
        __syncthreads();    // implicit vmcnt(0)+lgkmcnt(0)
        const u16* sb = smem + (tk & 1) * 32768;
        if (tk + 1 < NT) {
            const int kn = (tk + 1) << 5;
            u16* d = smem + ((tk + 1) & 1) * 32768 + t * 8;
            gload16(gAh + kn, d);
            gload16(gAl + kn, d + 8192);
            gload16(gBh + kn, d + 16384);
            gload16(gBl + kn, d + 24576);
        }
        const u16* sAh = sb;
        const u16* sAl = sb + 8192;
        const u16* sBh = sb + 16384;
        const u16* sBl = sb + 24576;

        short8 bh[4], bl[4];
        #pragma unroll
        for (int n = 0; n < 4; n++) {
            bh[n] = ldfrag(sBh, wn + n * 16 + lr, lg);
            bl[n] = ldfrag(sBl, wn + n * 16 + lr, lg);
        }
        __builtin_amdgcn_s_setprio(1);
        #pragma unroll
        for (int m = 0; m < 4; m++) {
            const short8 ah = ldfrag(sAh, wm + m * 16 + lr, lg);
            const short8 al = ldfrag(sAl, wm + m * 16 + lr, lg);
            #pragma unroll
            for (int n = 0; n < 4; n++) {
                acc[m][n] = MFB(ah, bh[n], acc[m][n]);
                acc[m][n] = MFB(ah, bl[n], acc[m][n]);
                acc[m][n] = MFB(al, bh[n], acc[m][n]);
            }
        }
        __builtin_amdgcn_s_setprio(0);
    }

    // ---- epilogue ----
    #pragma unroll
    for (int m = 0; m < 4; m++) {
        #pragma unroll
        for (int n = 0; n < 4; n++) {
            #pragma unroll
            for (int r = 0; r < 4; r++) {
                const int grow = row0 + wm + m * 16 + lg * 4 + r;
                const int gcol = col0 + wn + n * 16 + lr;
                Cf[(long)grow * ldc + gcol] = alpha * acc[m][n][r];
            }
        }
    }
}

// merged float -> (hi,lo) bf16 split for X, R, E in one launch
__global__ __launch_bounds__(256)
void split_rm3(const float* __restrict__ in0, u16* __restrict__ hi0, u16* __restrict__ lo0, long n0,
               const float* __restrict__ in1, u16* __restrict__ hi1, u16* __restrict__ lo1, long n1,
               const float* __restrict__ in2, u16* __restrict__ hi2, u16* __restrict__ lo2)
{
    long i = ((long)blockIdx.x * 256 + threadIdx.x) * 4;
    const float* in; u16 *hi, *lo;
    if (i < n0)           { in = in0; hi = hi0; lo = lo0; }
    else if (i < n0 + n1) { i -= n0; in = in1; hi = hi1; lo = lo1; }
    else                  { i -= n0 + n1; in = in2; hi = hi2; lo = lo2; }
    const float4 v = *reinterpret_cast<const float4*>(in + i);
    ushort4 h, l;
    split2(v.x, h.x, l.x);
    split2(v.y, h.y, l.y);
    split2(v.z, h.z, l.z);
    split2(v.w, h.w, l.w);
    *reinterpret_cast<ushort4*>(hi + i) = h;
    *reinterpret_cast<ushort4*>(lo + i) = l;
}

// sum 4 partial fp32 buffers (stride n) -> (hi,lo) bf16
__global__ __launch_bounds__(256)
void reduce4_split(const float* __restrict__ p, u16* __restrict__ hi, u16* __restrict__ lo,
                   long n)
{
    const long i = ((long)blockIdx.x * 256 + threadIdx.x) * 4;
    const float4 a = *reinterpret_cast<const float4*>(p + i);
    const float4 b = *reinterpret_cast<const float4*>(p + n + i);
    const float4 c = *reinterpret_cast<const float4*>(p + 2 * n + i);
    const float4 d = *reinterpret_cast<const float4*>(p + 3 * n + i);
    ushort4 h, l;
    split2((a.x + b.x) + (c.x + d.x), h.x, l.x);
    split2((a.y + b.y) + (c.y + d.y), h.y, l.y);
    split2((a.z + b.z) + (c.z + d.z), h.z, l.z);
    split2((a.w + b.w) + (c.w + d.w), h.w, l.w);
    *reinterpret_cast<ushort4*>(hi + i) = h;
    *reinterpret_cast<ushort4*>(lo + i) = l;
}

// float (R x C) -> transposed (C x R) bf16 hi (+lo if HILO); batched via blockIdx.z
template<bool HILO>
__global__ __launch_bounds__(256)
void split_tr(const float* __restrict__ in, u16* __restrict__ hi, u16* __restrict__ lo,
              int R, int C, long sIn, long sOut)
{
    in += (long)blockIdx.z * sIn;
    hi += (long)blockIdx.z * sOut;
    if (HILO) lo += (long)blockIdx.z * sOut;

    __shared__ float tile[32][33];
    const int tx = threadIdx.x & 31, ty = threadIdx.x >> 5;   // 32 x 8
    const int r0 = blockIdx.y * 32, c0 = blockIdx.x * 32;

    #pragma unroll
    for (int j = 0; j < 4; j++)
        tile[ty * 4 + j][tx] = in[(long)(r0 + ty * 4 + j) * C + c0 + tx];
    __syncthreads();

    #pragma unroll
    for (int j = 0; j < 4; j++) {
        const int oc = ty * 4 + j;
        const float v = tile[tx][oc];
        u16 h, l; split2(v, h, l);
        const long o = (long)(c0 + oc) * R + r0 + tx;
        hi[o] = h;
        if (HILO) lo[o] = l;
    }
}

// row softmax over 2048 fp32 logits -> bf16 (hi only) probabilities
__global__ __launch_bounds__(256)
void softmax_hi(const float* __restrict__ S, u16* __restrict__ hi)
{
    const int NC = 2048;
    const long base = (long)blockIdx.x * NC;
    const float* p = S + base;
    const int tid = threadIdx.x;

    float4 v0 = reinterpret_cast<const float4*>(p)[tid];
    float4 v1 = reinterpret_cast<const float4*>(p)[tid + 256];

    float m = fmaxf(fmaxf(fmaxf(v0.x, v0.y), fmaxf(v0.z, v0.w)),
                    fmaxf(fmaxf(v1.x, v1.y), fmaxf(v1.z, v1.w)));
    #pragma unroll
    for (int off = 1; off < 64; off <<= 1)
        m = fmaxf(m, __shfl_xor(m, off));

    __shared__ float redm[4];
    __shared__ float reds[4];
    const int wave = tid >> 6, lane = tid & 63;
    if (lane == 0) redm[wave] = m;
    __syncthreads();
    m = fmaxf(fmaxf(redm[0], redm[1]), fmaxf(redm[2], redm[3]));

    v0.x = __expf(v0.x - m); v0.y = __expf(v0.y - m);
    v0.z = __expf(v0.z - m); v0.w = __expf(v0.w - m);
    v1.x = __expf(v1.x - m); v1.y = __expf(v1.y - m);
    v1.z = __expf(v1.z - m); v1.w = __expf(v1.w - m);

    float s = (v0.x + v0.y + v0.z + v0.w) + (v1.x + v1.y + v1.z + v1.w);
    #pragma unroll
    for (int off = 1; off < 64; off <<= 1)
        s += __shfl_xor(s, off);
    if (lane == 0) reds[wave] = s;
    __syncthreads();
    s = (reds[0] + reds[1]) + (reds[2] + reds[3]);

    const float inv = 1.0f / s;
    ushort4 h0, h1;
    h0.x = f2bf(v0.x * inv); h0.y = f2bf(v0.y * inv);
    h0.z = f2bf(v0.z * inv); h0.w = f2bf(v0.w * inv);
    h1.x = f2bf(v1.x * inv); h1.y = f2bf(v1.y * inv);
    h1.z = f2bf(v1.z * inv); h1.w = f2bf(v1.w * inv);

    reinterpret_cast<ushort4*>(hi + base)[tid]       = h0;
    reinterpret_cast<ushort4*>(hi + base)[tid + 256] = h1;
}

extern "C" void kernel_launch(void* const* d_in, const int* in_sizes, int n_in,
                              void* d_out, int out_size, void* d_ws, size_t ws_size,
                              hipStream_t stream)
{
    (void)in_sizes; (void)n_in; (void)out_size; (void)ws_size;
    const float* X = (const float*)d_in[0];   // (4,2048,1024)
    const float* R = (const float*)d_in[1];   // (1024,1024)
    const float* E = (const float*)d_in[2];   // (1024,1024)
    float* out = (float*)d_out;

    const int B = 4, SQ = 2048, D = 1024;
    const long NDX = (long)B * SQ * D;        // 8388608
    const long DD  = (long)D * D;             // 1048576
    const long SS  = (long)B * SQ * SQ;       // 16777216
    const long M16 = 8388608;                 // u16 elems per 16 MiB

    u16* wsu = (u16*)d_ws;
    // [0,32MB):  Xhi(16) Xlo(16)      -> after S-gemm: Xthi at [0,16)
    // [32,64MB): Rhi Rlo Ehi Elo (8)  -> Yhi(16) Ylo(16) -> Shi(32)
    // [64,128MB): Wpart(16) Wthi/Wtlo(4, at 80MB) -> Sf(64)
    u16* Xhi  = wsu;
    u16* Xlo  = Xhi + NDX;
    u16* Rhi  = wsu + 2 * M16;                // 32MB
    u16* Rlo  = Rhi + DD;
    u16* Ehi  = Rlo + DD;
    u16* Elo  = Ehi + DD;
    u16* Yhi  = wsu + 2 * M16;                // 32MB (R/E dead by then)
    u16* Ylo  = Yhi + NDX;
    u16* Shi  = wsu + 2 * M16;                // 32MB (Y dead by then)
    u16* Xthi = wsu;                          // (X splits dead by then)
    float* Wpart = (float*)(wsu + 4 * M16);   // 64MB: 4 x DD fp32 = 16MB
    u16* Wthi = wsu + 5 * M16;                // 80MB
    u16* Wtlo = Wthi + DD;
    float* Sf = (float*)(wsu + 4 * M16);      // 64MB..128MB (Wpart/Wt dead)

    dim3 thr(256);

    // split all three inputs in ONE launch (X 8192 blocks + R 1024 + E 1024)
    split_rm3<<<dim3((unsigned)((NDX + 2 * DD) / 1024)), thr, 0, stream>>>(
        X, Xhi, Xlo, NDX, R, Rhi, Rlo, DD, E, Ehi, Elo);

    // Wt = E @ R^T  (= (R E^T)^T), K-split x4 into fp32 partials + reduce
    gemm_split<EP_F32, true, 1><<<dim3(D / 128, D / 128, 4), thr, 0, stream>>>(
        Ehi, Elo, Rhi, Rlo, Wpart, nullptr, nullptr,
        256, D, D, D, 256, 256, DD, 1.0f);
    reduce4_split<<<dim3((unsigned)(DD / 1024)), thr, 0, stream>>>(Wpart, Wthi, Wtlo, DD);

    // Y = X @ Wt^T = X R E^T  -> hi/lo (8192 x 1024)
    gemm_split<EP_HILO, true, 1><<<dim3(D / 128, (B * SQ) / 128, 1), thr, 0, stream>>>(
        Xhi, Xlo, Wthi, Wtlo, nullptr, Yhi, Ylo,
        D, D, D, D, 0, 0, 0, 1.0f);

    // S = Y X^T / 32 (fp32 logits; B operand is X as stored) — 16-wave 256^2
    gemm_triple_256<<<dim3(SQ / 256, SQ / 256, B), dim3(1024), 0, stream>>>(
        Yhi, Ylo, Xhi, Xlo, Sf,
        D, D, D, SQ,
        (long)SQ * D, (long)SQ * D, (long)SQ * SQ, 0.03125f);

    // softmax fp32 -> probability hi into Shi (Y dead)
    softmax_hi<<<dim3(B * SQ), thr, 0, stream>>>(Sf, Shi);

    // Xt (per batch 1024x2048) hi-only (X splits dead)
    split_tr<false><<<dim3(D / 32, SQ / 32, B), thr, 0, stream>>>(
        X, Xthi, nullptr, SQ, D, (long)SQ * D, (long)SQ * D);

    // O = sigmoid(S @ X), single-bf16 MFMA, BK=64 (KH=2)
    gemm_split<EP_SIG, false, 2><<<dim3(D / 128, SQ / 128, B), thr, 0, stream>>>(
        Shi, nullptr, Xthi, nullptr, out, nullptr, nullptr,
        SQ, SQ, SQ, D,
        (long)SQ * SQ, (long)SQ * D, (long)SQ * D, 1.0f);
}